// Round 1
// baseline (1786.585 us; speedup 1.0000x reference)
//
#include <hip/hip_runtime.h>

#define N_NODES 50000
#define N_EDGES 800000
#define IN_CH   128
#define HID_CH  512
#define OUT_CH  256

// ---------------------------------------------------------------------------
// Kernel 1: W12[i][j] = sum_k W1[i][k] * W2[k][j]   (i<128)
//           b2[j]     = sum_k b1[k]   * W2[k][j]    (block i==128)
// grid = 129 blocks x 256 threads; trivial FLOPs, runs once per call.
// ---------------------------------------------------------------------------
__global__ void build_w12(const float* __restrict__ W1,
                          const float* __restrict__ b1,
                          const float* __restrict__ W2,
                          float* __restrict__ W12,
                          float* __restrict__ b2) {
    const int i = blockIdx.x;        // 0..128 (128 == bias row)
    const int j = threadIdx.x;       // 0..255
    const float* arow = (i < IN_CH) ? (W1 + (size_t)i * HID_CH) : b1;
    float acc = 0.f;
#pragma unroll 8
    for (int k = 0; k < HID_CH; ++k)
        acc = fmaf(arow[k], W2[(size_t)k * OUT_CH + j], acc);
    if (i < IN_CH) W12[i * OUT_CH + j] = acc;
    else           b2[j] = acc;
}

// ---------------------------------------------------------------------------
// Kernel 2: scatter-add  agg[dst] += x[src]   (agg pre-initialized to x)
// 32 threads per edge, float4 per thread -> 4 atomicAdd f32 each.
// ---------------------------------------------------------------------------
__global__ void scatter_add(const float* __restrict__ x,
                            const int* __restrict__ ei,
                            float* __restrict__ agg) {
    const unsigned gid = blockIdx.x * blockDim.x + threadIdx.x;
    const unsigned e = gid >> 5;          // edge id
    const unsigned c = (gid & 31) << 2;   // channel offset (0,4,...,124)
    if (e >= N_EDGES) return;
    const int src = ei[e];
    const int dst = ei[N_EDGES + e];
    const float4 v = *(const float4*)(x + (size_t)src * IN_CH + c);
    float* p = agg + (size_t)dst * IN_CH + c;
    atomicAdd(p + 0, v.x);
    atomicAdd(p + 1, v.y);
    atomicAdd(p + 2, v.z);
    atomicAdd(p + 3, v.w);
}

// ---------------------------------------------------------------------------
// Kernel 3: out = agg @ W12 + b2      [50000,128] x [128,256]
// grid = (256, 2): blockIdx.y selects a 128-col half of W12 staged in LDS
// (64 KB -> 2 blocks/CU). 512 threads = 8 waves; each wave computes 4 nodes
// per iteration. Activation row held as float2/lane, broadcast via readlane.
// ---------------------------------------------------------------------------
__global__ __launch_bounds__(512) void mlp_out(const float* __restrict__ agg,
                                               const float* __restrict__ W12,
                                               const float* __restrict__ b2,
                                               float* __restrict__ out) {
    const int half = blockIdx.y;                 // col offset = half*128
    __shared__ float w[IN_CH][128];              // 64 KB
    {
        const float* src = W12 + half * 128;
        for (int i = threadIdx.x; i < IN_CH * 32; i += 512) {
            const int r = i >> 5;
            const int c = (i & 31) << 2;
            *(float4*)&w[r][c] = *(const float4*)(src + (size_t)r * OUT_CH + c);
        }
    }
    __syncthreads();

    const int wave  = threadIdx.x >> 6;
    const int lane  = threadIdx.x & 63;
    const int nwav  = gridDim.x * 8;
    const int gwave = blockIdx.x * 8 + wave;

    const float2 bb = *(const float2*)(b2 + half * 128 + lane * 2);

    // 50000 % 4 == 0: no tail handling needed
    const int ngroups = N_NODES / 4;             // 12500
    for (int g = gwave; g < ngroups; g += nwav) {
        const int n0 = g * 4;
        float2 a[4];
#pragma unroll
        for (int n = 0; n < 4; ++n)
            a[n] = *(const float2*)(agg + (size_t)(n0 + n) * IN_CH + lane * 2);

        float2 acc[4];
#pragma unroll
        for (int n = 0; n < 4; ++n) acc[n] = make_float2(0.f, 0.f);

#pragma unroll
        for (int k = 0; k < IN_CH; ++k) {
            const float2 wk = *(const float2*)&w[k][lane * 2];
#pragma unroll
            for (int n = 0; n < 4; ++n) {
                const int bits = (k & 1) ? __float_as_int(a[n].y)
                                         : __float_as_int(a[n].x);
                const float ak = __int_as_float(
                    __builtin_amdgcn_readlane(bits, k >> 1));
                acc[n].x = fmaf(ak, wk.x, acc[n].x);
                acc[n].y = fmaf(ak, wk.y, acc[n].y);
            }
        }
#pragma unroll
        for (int n = 0; n < 4; ++n) {
            float2 o;
            o.x = acc[n].x + bb.x;
            o.y = acc[n].y + bb.y;
            *(float2*)(out + (size_t)(n0 + n) * OUT_CH + half * 128 + lane * 2) = o;
        }
    }
}

// ---------------------------------------------------------------------------
extern "C" void kernel_launch(void* const* d_in, const int* in_sizes, int n_in,
                              void* d_out, int out_size, void* d_ws, size_t ws_size,
                              hipStream_t stream) {
    const float* x  = (const float*)d_in[0];
    const int*   ei = (const int*)d_in[1];      // [2, N_EDGES], int32 per harness
    const float* W1 = (const float*)d_in[2];
    const float* b1 = (const float*)d_in[3];
    const float* W2 = (const float*)d_in[4];
    float* out = (float*)d_out;

    // workspace layout
    float* agg = (float*)d_ws;                                   // 25,600,000 B
    float* W12 = (float*)((char*)d_ws + (size_t)N_NODES * IN_CH * 4);  // 131,072 B
    float* b2  = W12 + IN_CH * OUT_CH;                           // 1,024 B

    // 1) collapse the MLP: W12 = W1@W2, b2 = b1@W2
    build_w12<<<dim3(IN_CH + 1), dim3(256), 0, stream>>>(W1, b1, W2, W12, b2);

    // 2) agg = x  (residual folded in), then agg[dst] += x[src]
    hipMemcpyAsync(agg, x, (size_t)N_NODES * IN_CH * sizeof(float),
                   hipMemcpyDeviceToDevice, stream);
    {
        const unsigned total = N_EDGES * 32u;
        scatter_add<<<dim3(total / 256), dim3(256), 0, stream>>>(x, ei, agg);
    }

    // 3) out = agg @ W12 + b2
    mlp_out<<<dim3(256, 2), dim3(512), 0, stream>>>(agg, W12, b2, out);
}

// Round 2
// 674.008 us; speedup vs baseline: 2.6507x; 2.6507x over previous
//
#include <hip/hip_runtime.h>

#define N_NODES 50000
#define N_EDGES 800000
#define IN_CH   128
#define HID_CH  512
#define OUT_CH  256

// ---------------------------------------------------------------------------
// Kernel 1: W12[i][j] = sum_k W1[i][k] * W2[k][j]   (i<128)
//           b2[j]     = sum_k b1[k]   * W2[k][j]    (block i==128)
// ---------------------------------------------------------------------------
__global__ void build_w12(const float* __restrict__ W1,
                          const float* __restrict__ b1,
                          const float* __restrict__ W2,
                          float* __restrict__ W12,
                          float* __restrict__ b2) {
    const int i = blockIdx.x;        // 0..128 (128 == bias row)
    const int j = threadIdx.x;       // 0..255
    const float* arow = (i < IN_CH) ? (W1 + (size_t)i * HID_CH) : b1;
    float acc = 0.f;
#pragma unroll 8
    for (int k = 0; k < HID_CH; ++k)
        acc = fmaf(arow[k], W2[(size_t)k * OUT_CH + j], acc);
    if (i < IN_CH) W12[i * OUT_CH + j] = acc;
    else           b2[j] = acc;
}

// ---------------------------------------------------------------------------
// CSR build: histogram of dst -> rowptr[dst+1]  (int atomics, cheap)
// ---------------------------------------------------------------------------
__global__ void hist_dst(const int* __restrict__ ei, int* __restrict__ rowptr) {
    const int e = blockIdx.x * 256 + threadIdx.x;
    if (e < N_EDGES) atomicAdd(&rowptr[ei[N_EDGES + e] + 1], 1);
}

// Single-block inclusive scan over rowptr[1..N_NODES] (degrees -> offsets).
// 1024 threads x 49 elements each covers 50176 >= 50000.
__global__ __launch_bounds__(1024) void scan_rowptr(int* __restrict__ rowptr) {
    __shared__ int sums[1024];
    const int t = threadIdx.x;
    const int CH = (N_NODES + 1023) / 1024;        // 49
    const int beg = t * CH;
    const int end = (beg + CH < N_NODES) ? beg + CH : N_NODES;
    int s = 0;
    for (int i = beg; i < end; ++i) s += rowptr[i + 1];
    sums[t] = s;
    __syncthreads();
    // Hillis-Steele inclusive scan of per-thread sums
    for (int off = 1; off < 1024; off <<= 1) {
        int u = (t >= off) ? sums[t - off] : 0;
        __syncthreads();
        sums[t] += u;
        __syncthreads();
    }
    int run = sums[t] - s;                         // exclusive offset
    for (int i = beg; i < end; ++i) {
        run += rowptr[i + 1];
        rowptr[i + 1] = run;
    }
    // rowptr[0] stays 0 (from memset)
}

// Scatter edges into CSR slots. cursor pre-copied from rowptr[0..N-1].
__global__ void fill_csr(const int* __restrict__ ei, int* __restrict__ cursor,
                         int* __restrict__ srcidx) {
    const int e = blockIdx.x * 256 + threadIdx.x;
    if (e >= N_EDGES) return;
    const int dst = ei[N_EDGES + e];
    const int pos = atomicAdd(&cursor[dst], 1);
    srcidx[pos] = ei[e];
}

// ---------------------------------------------------------------------------
// Gather: one wave per node. agg[n] = x[n] + sum_{e in in(n)} x[src(e)]
// Lane l holds channels [2l, 2l+1] (float2) -> 512B coalesced row reads.
// ---------------------------------------------------------------------------
__global__ __launch_bounds__(256) void gather_rows(const float* __restrict__ x,
                                                   const int* __restrict__ rowptr,
                                                   const int* __restrict__ srcidx,
                                                   float* __restrict__ agg) {
    const int w    = (blockIdx.x * 256 + threadIdx.x) >> 6;   // node id
    const int lane = threadIdx.x & 63;
    if (w >= N_NODES) return;
    const int beg = rowptr[w];
    const int end = rowptr[w + 1];
    float2 acc = *(const float2*)(x + (size_t)w * IN_CH + lane * 2);
    for (int e = beg; e < end; ++e) {
        const int s = srcidx[e];
        const float2 v = *(const float2*)(x + (size_t)s * IN_CH + lane * 2);
        acc.x += v.x;
        acc.y += v.y;
    }
    *(float2*)(agg + (size_t)w * IN_CH + lane * 2) = acc;
}

// ---------------------------------------------------------------------------
// out = agg @ W12 + b2      [50000,128] x [128,256]
// ---------------------------------------------------------------------------
__global__ __launch_bounds__(512) void mlp_out(const float* __restrict__ agg,
                                               const float* __restrict__ W12,
                                               const float* __restrict__ b2,
                                               float* __restrict__ out) {
    const int half = blockIdx.y;                 // col offset = half*128
    __shared__ float w[IN_CH][128];              // 64 KB
    {
        const float* src = W12 + half * 128;
        for (int i = threadIdx.x; i < IN_CH * 32; i += 512) {
            const int r = i >> 5;
            const int c = (i & 31) << 2;
            *(float4*)&w[r][c] = *(const float4*)(src + (size_t)r * OUT_CH + c);
        }
    }
    __syncthreads();

    const int wave  = threadIdx.x >> 6;
    const int lane  = threadIdx.x & 63;
    const int nwav  = gridDim.x * 8;
    const int gwave = blockIdx.x * 8 + wave;

    const float2 bb = *(const float2*)(b2 + half * 128 + lane * 2);

    const int ngroups = N_NODES / 4;             // 12500
    for (int g = gwave; g < ngroups; g += nwav) {
        const int n0 = g * 4;
        float2 a[4];
#pragma unroll
        for (int n = 0; n < 4; ++n)
            a[n] = *(const float2*)(agg + (size_t)(n0 + n) * IN_CH + lane * 2);

        float2 acc[4];
#pragma unroll
        for (int n = 0; n < 4; ++n) acc[n] = make_float2(0.f, 0.f);

#pragma unroll
        for (int k = 0; k < IN_CH; ++k) {
            const float2 wk = *(const float2*)&w[k][lane * 2];
#pragma unroll
            for (int n = 0; n < 4; ++n) {
                const int bits = (k & 1) ? __float_as_int(a[n].y)
                                         : __float_as_int(a[n].x);
                const float ak = __int_as_float(
                    __builtin_amdgcn_readlane(bits, k >> 1));
                acc[n].x = fmaf(ak, wk.x, acc[n].x);
                acc[n].y = fmaf(ak, wk.y, acc[n].y);
            }
        }
#pragma unroll
        for (int n = 0; n < 4; ++n) {
            float2 o;
            o.x = acc[n].x + bb.x;
            o.y = acc[n].y + bb.y;
            *(float2*)(out + (size_t)(n0 + n) * OUT_CH + half * 128 + lane * 2) = o;
        }
    }
}

// ---------------------------------------------------------------------------
extern "C" void kernel_launch(void* const* d_in, const int* in_sizes, int n_in,
                              void* d_out, int out_size, void* d_ws, size_t ws_size,
                              hipStream_t stream) {
    const float* x  = (const float*)d_in[0];
    const int*   ei = (const int*)d_in[1];      // [2, N_EDGES] int32
    const float* W1 = (const float*)d_in[2];
    const float* b1 = (const float*)d_in[3];
    const float* W2 = (const float*)d_in[4];
    float* out = (float*)d_out;

    // workspace layout (bytes)             offset        size
    char* ws = (char*)d_ws;
    float* agg    = (float*)(ws + 0);                    // 25,600,000
    float* W12    = (float*)(ws + 25600000);             //    131,072
    float* b2     = (float*)(ws + 25731072);             //      1,024
    int*   rowptr = (int*)  (ws + 25732096);             //    200,016 (50001 ints)
    int*   cursor = (int*)  (ws + 25932112);             //    200,000
    int*   srcidx = (int*)  (ws + 26132112);             //  3,200,000  -> total ~29.3 MB

    // 1) collapse the MLP: W12 = W1@W2, b2 = b1@W2  (independent of CSR path)
    build_w12<<<dim3(IN_CH + 1), dim3(256), 0, stream>>>(W1, b1, W2, W12, b2);

    // 2) CSR build: memset degrees, histogram, scan, copy cursors, fill
    hipMemsetAsync(rowptr, 0, (N_NODES + 1) * sizeof(int), stream);
    hist_dst<<<dim3((N_EDGES + 255) / 256), dim3(256), 0, stream>>>(ei, rowptr);
    scan_rowptr<<<dim3(1), dim3(1024), 0, stream>>>(rowptr);
    hipMemcpyAsync(cursor, rowptr, N_NODES * sizeof(int),
                   hipMemcpyDeviceToDevice, stream);
    fill_csr<<<dim3((N_EDGES + 255) / 256), dim3(256), 0, stream>>>(ei, cursor, srcidx);

    // 3) gather (residual folded in): agg[n] = x[n] + sum x[src]
    {
        const long long threads = (long long)N_NODES * 64;
        gather_rows<<<dim3((unsigned)((threads + 255) / 256)), dim3(256), 0, stream>>>(
            x, rowptr, srcidx, agg);
    }

    // 4) out = agg @ W12 + b2
    mlp_out<<<dim3(256, 2), dim3(512), 0, stream>>>(agg, W12, b2, out);
}

// Round 3
// 254.136 us; speedup vs baseline: 7.0300x; 2.6522x over previous
//
#include <hip/hip_runtime.h>

#define N_NODES 50000
#define N_EDGES 800000
#define IN_CH   128
#define HID_CH  512
#define OUT_CH  256

typedef __attribute__((ext_vector_type(8))) short bf16x8;
typedef __attribute__((ext_vector_type(4))) float f32x4;

static __device__ __forceinline__ ushort f2bf(float f) {
    uint u = __float_as_uint(f);
    uint r = u + 0x7fffu + ((u >> 16) & 1u);   // RNE; inputs are finite
    return (ushort)(r >> 16);
}

// ---------------------------------------------------------------------------
// W12t[j][i] = sum_k W1[i][k]*W2[k][j]  (bf16, TRANSPOSED: [256][128])
// b2[j]     = sum_k b1[k]*W2[k][j]     (f32)
// ---------------------------------------------------------------------------
__global__ void build_w12(const float* __restrict__ W1,
                          const float* __restrict__ b1,
                          const float* __restrict__ W2,
                          ushort* __restrict__ W12t,
                          float* __restrict__ b2) {
    const int i = blockIdx.x;        // 0..128 (128 == bias row)
    const int j = threadIdx.x;       // 0..255
    const float* arow = (i < IN_CH) ? (W1 + (size_t)i * HID_CH) : b1;
    float acc = 0.f;
#pragma unroll 8
    for (int k = 0; k < HID_CH; ++k)
        acc = fmaf(arow[k], W2[(size_t)k * OUT_CH + j], acc);
    if (i < IN_CH) W12t[(size_t)j * IN_CH + i] = f2bf(acc);
    else           b2[j] = acc;
}

// ---------------------------------------------------------------------------
// x (f32) -> xb (bf16)
// ---------------------------------------------------------------------------
__global__ void cvt_bf16(const float* __restrict__ x, ushort* __restrict__ xb) {
    const int i = blockIdx.x * 256 + threadIdx.x;      // group of 4 elements
    if (i >= N_NODES * IN_CH / 4) return;
    const float4 v = *(const float4*)(x + (size_t)i * 4);
    ushort4 o;
    o.x = f2bf(v.x); o.y = f2bf(v.y); o.z = f2bf(v.z); o.w = f2bf(v.w);
    *(ushort4*)(xb + (size_t)i * 4) = o;
}

// ---------------------------------------------------------------------------
// CSR build
// ---------------------------------------------------------------------------
__global__ void hist_dst(const int* __restrict__ ei, int* __restrict__ rowptr) {
    const int e = blockIdx.x * 256 + threadIdx.x;
    if (e < N_EDGES) atomicAdd(&rowptr[ei[N_EDGES + e] + 1], 1);
}

__global__ __launch_bounds__(1024) void scan_rowptr(int* __restrict__ rowptr) {
    __shared__ int sums[1024];
    const int t = threadIdx.x;
    const int CH = (N_NODES + 1023) / 1024;        // 49
    const int beg = t * CH;
    const int end = (beg + CH < N_NODES) ? beg + CH : N_NODES;
    int s = 0;
    for (int i = beg; i < end; ++i) s += rowptr[i + 1];
    sums[t] = s;
    __syncthreads();
    for (int off = 1; off < 1024; off <<= 1) {
        int u = (t >= off) ? sums[t - off] : 0;
        __syncthreads();
        sums[t] += u;
        __syncthreads();
    }
    int run = sums[t] - s;
    for (int i = beg; i < end; ++i) {
        run += rowptr[i + 1];
        rowptr[i + 1] = run;
    }
}

__global__ void fill_csr(const int* __restrict__ ei, int* __restrict__ cursor,
                         int* __restrict__ srcidx) {
    const int e = blockIdx.x * 256 + threadIdx.x;
    if (e >= N_EDGES) return;
    const int dst = ei[N_EDGES + e];
    const int pos = atomicAdd(&cursor[dst], 1);
    srcidx[pos] = ei[e];
}

// ---------------------------------------------------------------------------
// Gather (bf16 rows, f32 accumulate): aggb[n] = x[n] + sum_{e in in(n)} x[src]
// One wave per node; lane l holds channels [2l,2l+1] packed in one uint.
// ---------------------------------------------------------------------------
__global__ __launch_bounds__(256) void gather_bf16(const ushort* __restrict__ xb,
                                                   const int* __restrict__ rowptr,
                                                   const int* __restrict__ srcidx,
                                                   ushort* __restrict__ aggb) {
    const int node = (int)((blockIdx.x * 256u + threadIdx.x) >> 6);
    const int lane = threadIdx.x & 63;
    if (node >= N_NODES) return;
    const uint* xrow = (const uint*)xb;            // 64 uints per node row
    const uint self = xrow[(size_t)node * 64 + lane];
    float ax = __uint_as_float(self << 16);
    float ay = __uint_as_float(self & 0xffff0000u);
    int e = rowptr[node];
    const int end = rowptr[node + 1];
    for (; e + 4 <= end; e += 4) {
        const int s0 = srcidx[e + 0];
        const int s1 = srcidx[e + 1];
        const int s2 = srcidx[e + 2];
        const int s3 = srcidx[e + 3];
        const uint v0 = xrow[(size_t)s0 * 64 + lane];
        const uint v1 = xrow[(size_t)s1 * 64 + lane];
        const uint v2 = xrow[(size_t)s2 * 64 + lane];
        const uint v3 = xrow[(size_t)s3 * 64 + lane];
        ax += __uint_as_float(v0 << 16); ay += __uint_as_float(v0 & 0xffff0000u);
        ax += __uint_as_float(v1 << 16); ay += __uint_as_float(v1 & 0xffff0000u);
        ax += __uint_as_float(v2 << 16); ay += __uint_as_float(v2 & 0xffff0000u);
        ax += __uint_as_float(v3 << 16); ay += __uint_as_float(v3 & 0xffff0000u);
    }
    for (; e < end; ++e) {
        const uint v = xrow[(size_t)srcidx[e] * 64 + lane];
        ax += __uint_as_float(v << 16); ay += __uint_as_float(v & 0xffff0000u);
    }
    const uint packed = ((uint)f2bf(ay) << 16) | (uint)f2bf(ax);
    ((uint*)aggb)[(size_t)node * 64 + lane] = packed;
}

// ---------------------------------------------------------------------------
// out[50000,256] = aggb @ W12 + b2   via bf16 MFMA 16x16x32.
// Block: 256 rows x 256 cols, 8 waves (2Mx4N -> wave = 64 rows x 128 cols).
// Full K=128 of Bt staged in 64KB LDS, XOR-swizzled 16B chunks (T2).
// ---------------------------------------------------------------------------
__global__ __launch_bounds__(512) void mfma_gemm(const ushort* __restrict__ aggb,
                                                 const ushort* __restrict__ w12t,
                                                 const float* __restrict__ b2,
                                                 float* __restrict__ out) {
    __shared__ ushort bt[256 * 128];               // 64 KB
    const int tid = threadIdx.x;

    // stage Bt[n][k] (row = 256B = 16 chunks of 16B); chunk s -> slot s^(n&7)
#pragma unroll
    for (int it = 0; it < 8; ++it) {
        const int i = tid + it * 512;              // 0..4095
        const int n = i >> 4, s = i & 15;
        const uint4 v = *(const uint4*)(w12t + (size_t)i * 8);
        *(uint4*)(&bt[(n << 7) + ((s ^ (n & 7)) << 3)]) = v;
    }
    __syncthreads();

    const int lane = tid & 63;
    const int w    = tid >> 6;
    const int rbase = blockIdx.x * 256 + (w >> 1) * 64;
    const int cbase = (w & 1) * 128;
    const int l15 = lane & 15;
    const int oct = lane >> 4;

    f32x4 acc[4][8];
#pragma unroll
    for (int m = 0; m < 4; ++m)
#pragma unroll
        for (int n = 0; n < 8; ++n)
            acc[m][n] = (f32x4){0.f, 0.f, 0.f, 0.f};

#pragma unroll
    for (int kk = 0; kk < 4; ++kk) {               // k = kk*32 + oct*8 + j
        bf16x8 afr[4];
#pragma unroll
        for (int m = 0; m < 4; ++m) {
            int row = rbase + m * 16 + l15;
            row = row < N_NODES ? row : N_NODES - 1;   // tail clamp (discarded)
            afr[m] = *(const bf16x8*)(aggb + (size_t)row * IN_CH + kk * 32 + oct * 8);
        }
#pragma unroll
        for (int n = 0; n < 8; ++n) {
            const int col  = cbase + n * 16 + l15;
            const int slot = (kk * 4 + oct) ^ (col & 7);
            const bf16x8 bfr = *(const bf16x8*)(&bt[(col << 7) + (slot << 3)]);
#pragma unroll
            for (int m = 0; m < 4; ++m)
                acc[m][n] = __builtin_amdgcn_mfma_f32_16x16x32_bf16(
                    afr[m], bfr, acc[m][n], 0, 0, 0);
        }
    }

    // epilogue: D col = lane&15, row = oct*4 + r  (verified m89/m91 layout)
#pragma unroll
    for (int m = 0; m < 4; ++m) {
        const int row0 = rbase + m * 16 + oct * 4;
#pragma unroll
        for (int n = 0; n < 8; ++n) {
            const int col = cbase + n * 16 + l15;
            const float bias = b2[col];
#pragma unroll
            for (int r = 0; r < 4; ++r) {
                const int row = row0 + r;
                if (row < N_NODES)
                    out[(size_t)row * OUT_CH + col] = acc[m][n][r] + bias;
            }
        }
    }
}

// ---------------------------------------------------------------------------
extern "C" void kernel_launch(void* const* d_in, const int* in_sizes, int n_in,
                              void* d_out, int out_size, void* d_ws, size_t ws_size,
                              hipStream_t stream) {
    const float* x  = (const float*)d_in[0];
    const int*   ei = (const int*)d_in[1];      // [2, N_EDGES] int32
    const float* W1 = (const float*)d_in[2];
    const float* b1 = (const float*)d_in[3];
    const float* W2 = (const float*)d_in[4];
    float* out = (float*)d_out;

    // workspace layout (bytes)
    char* ws = (char*)d_ws;
    ushort* xb     = (ushort*)(ws + 0);                  // 12,800,000
    ushort* aggb   = (ushort*)(ws + 12800000);           // 12,800,000
    ushort* W12t   = (ushort*)(ws + 25600000);           //     65,536
    float*  b2     = (float*) (ws + 25665536);           //      1,024
    int*    rowptr = (int*)   (ws + 25666560);           //    200,004
    int*    cursor = (int*)   (ws + 25866564);           //    200,000
    int*    srcidx = (int*)   (ws + 26066564);           //  3,200,000 -> ~29.27 MB

    // 1) collapse MLP -> bf16 W12^T + f32 b2
    build_w12<<<dim3(IN_CH + 1), dim3(256), 0, stream>>>(W1, b1, W2, W12t, b2);

    // 2) x -> bf16
    cvt_bf16<<<dim3((N_NODES * IN_CH / 4 + 255) / 256), dim3(256), 0, stream>>>(x, xb);

    // 3) CSR build
    hipMemsetAsync(rowptr, 0, (N_NODES + 1) * sizeof(int), stream);
    hist_dst<<<dim3((N_EDGES + 255) / 256), dim3(256), 0, stream>>>(ei, rowptr);
    scan_rowptr<<<dim3(1), dim3(1024), 0, stream>>>(rowptr);
    hipMemcpyAsync(cursor, rowptr, N_NODES * sizeof(int),
                   hipMemcpyDeviceToDevice, stream);
    fill_csr<<<dim3((N_EDGES + 255) / 256), dim3(256), 0, stream>>>(ei, cursor, srcidx);

    // 4) gather (residual folded): aggb[n] = x[n] + sum x[src]   (bf16)
    gather_bf16<<<dim3(N_NODES * 64 / 256), dim3(256), 0, stream>>>(
        xb, rowptr, srcidx, aggb);

    // 5) out = aggb @ W12 + b2   (bf16 MFMA)
    mfma_gemm<<<dim3((N_NODES + 255) / 256), dim3(512), 0, stream>>>(
        aggb, W12t, b2, out);
}

// Round 4
// 176.518 us; speedup vs baseline: 10.1213x; 1.4397x over previous
//
#include <hip/hip_runtime.h>

#define N_NODES 50000
#define N_EDGES 800000
#define IN_CH   128
#define HID_CH  512
#define OUT_CH  256

#define SCAN_TILE 512
#define N_TILES   ((N_NODES + SCAN_TILE - 1) / SCAN_TILE)   // 98

typedef __attribute__((ext_vector_type(8))) short bf16x8;
typedef __attribute__((ext_vector_type(4))) float f32x4;

static __device__ __forceinline__ ushort f2bf(float f) {
    uint u = __float_as_uint(f);
    uint r = u + 0x7fffu + ((u >> 16) & 1u);   // RNE; inputs are finite
    return (ushort)(r >> 16);
}

// ---------------------------------------------------------------------------
// W12t[j][i] = sum_k W1[i][k]*W2[k][j]  (bf16, TRANSPOSED: [256][128])
// b2[j]     = sum_k b1[k]*W2[k][j]     (f32)
// ---------------------------------------------------------------------------
__global__ void build_w12(const float* __restrict__ W1,
                          const float* __restrict__ b1,
                          const float* __restrict__ W2,
                          ushort* __restrict__ W12t,
                          float* __restrict__ b2) {
    const int i = blockIdx.x;        // 0..128 (128 == bias row)
    const int j = threadIdx.x;       // 0..255
    const float* arow = (i < IN_CH) ? (W1 + (size_t)i * HID_CH) : b1;
    float acc = 0.f;
#pragma unroll 8
    for (int k = 0; k < HID_CH; ++k)
        acc = fmaf(arow[k], W2[(size_t)k * OUT_CH + j], acc);
    if (i < IN_CH) W12t[(size_t)j * IN_CH + i] = f2bf(acc);
    else           b2[j] = acc;
}

// ---------------------------------------------------------------------------
// x (f32) -> xb (bf16)
// ---------------------------------------------------------------------------
__global__ void cvt_bf16(const float* __restrict__ x, ushort* __restrict__ xb) {
    const int i = blockIdx.x * 256 + threadIdx.x;      // group of 4 elements
    if (i >= N_NODES * IN_CH / 4) return;
    const float4 v = *(const float4*)(x + (size_t)i * 4);
    ushort4 o;
    o.x = f2bf(v.x); o.y = f2bf(v.y); o.z = f2bf(v.z); o.w = f2bf(v.w);
    *(ushort4*)(xb + (size_t)i * 4) = o;
}

// ---------------------------------------------------------------------------
// CSR build
// ---------------------------------------------------------------------------
__global__ void hist_dst(const int* __restrict__ ei, int* __restrict__ rowptr) {
    const int e = blockIdx.x * 256 + threadIdx.x;
    if (e < N_EDGES) atomicAdd(&rowptr[ei[N_EDGES + e] + 1], 1);
}

// Stage A: per-tile inclusive scan of degrees (rowptr[i+1]), tile sums out.
__global__ __launch_bounds__(SCAN_TILE) void scan_tiles(int* __restrict__ rowptr,
                                                        int* __restrict__ tilesum) {
    __shared__ int s[SCAN_TILE];
    const int t = threadIdx.x;
    const int g = blockIdx.x * SCAN_TILE + t;          // element (node) index
    const int v = (g < N_NODES) ? rowptr[g + 1] : 0;
    s[t] = v;
    __syncthreads();
#pragma unroll
    for (int off = 1; off < SCAN_TILE; off <<= 1) {
        const int u = (t >= off) ? s[t - off] : 0;
        __syncthreads();
        s[t] += u;
        __syncthreads();
    }
    if (g < N_NODES) rowptr[g + 1] = s[t];
    if (t == SCAN_TILE - 1) tilesum[blockIdx.x] = s[t];
}

// Stage B: exclusive scan of the 98 tile sums (one small block).
__global__ __launch_bounds__(128) void scan_sums(int* __restrict__ tilesum) {
    __shared__ int s[128];
    const int t = threadIdx.x;
    const int v = (t < N_TILES) ? tilesum[t] : 0;
    s[t] = v;
    __syncthreads();
#pragma unroll
    for (int off = 1; off < 128; off <<= 1) {
        const int u = (t >= off) ? s[t - off] : 0;
        __syncthreads();
        s[t] += u;
        __syncthreads();
    }
    if (t < N_TILES) tilesum[t] = s[t] - v;            // exclusive
}

// Stage C: add tile offsets; also emit cursor[n] = rowptr[n] for fill_csr.
__global__ __launch_bounds__(SCAN_TILE) void add_offsets(int* __restrict__ rowptr,
                                                         const int* __restrict__ tilesum,
                                                         int* __restrict__ cursor) {
    const int g = blockIdx.x * SCAN_TILE + threadIdx.x;
    if (g >= N_NODES) return;
    const int v = rowptr[g + 1] + tilesum[blockIdx.x];
    rowptr[g + 1] = v;
    if (g + 1 < N_NODES) cursor[g + 1] = v;            // start of node g+1
    if (g == 0) cursor[0] = 0;
}

__global__ void fill_csr(const int* __restrict__ ei, int* __restrict__ cursor,
                         int* __restrict__ srcidx) {
    const int e = blockIdx.x * 256 + threadIdx.x;
    if (e >= N_EDGES) return;
    const int dst = ei[N_EDGES + e];
    const int pos = atomicAdd(&cursor[dst], 1);
    srcidx[pos] = ei[e];
}

// ---------------------------------------------------------------------------
// Gather (bf16 rows, f32 accumulate): aggb[n] = x[n] + sum_{e in in(n)} x[src]
// One wave per node; lane l holds channels [2l,2l+1] packed in one uint.
// ---------------------------------------------------------------------------
__global__ __launch_bounds__(256) void gather_bf16(const ushort* __restrict__ xb,
                                                   const int* __restrict__ rowptr,
                                                   const int* __restrict__ srcidx,
                                                   ushort* __restrict__ aggb) {
    const int node = (int)((blockIdx.x * 256u + threadIdx.x) >> 6);
    const int lane = threadIdx.x & 63;
    if (node >= N_NODES) return;
    const uint* xrow = (const uint*)xb;            // 64 uints per node row
    const uint self = xrow[(size_t)node * 64 + lane];
    float ax = __uint_as_float(self << 16);
    float ay = __uint_as_float(self & 0xffff0000u);
    int e = rowptr[node];
    const int end = rowptr[node + 1];
    for (; e + 4 <= end; e += 4) {
        const int s0 = srcidx[e + 0];
        const int s1 = srcidx[e + 1];
        const int s2 = srcidx[e + 2];
        const int s3 = srcidx[e + 3];
        const uint v0 = xrow[(size_t)s0 * 64 + lane];
        const uint v1 = xrow[(size_t)s1 * 64 + lane];
        const uint v2 = xrow[(size_t)s2 * 64 + lane];
        const uint v3 = xrow[(size_t)s3 * 64 + lane];
        ax += __uint_as_float(v0 << 16); ay += __uint_as_float(v0 & 0xffff0000u);
        ax += __uint_as_float(v1 << 16); ay += __uint_as_float(v1 & 0xffff0000u);
        ax += __uint_as_float(v2 << 16); ay += __uint_as_float(v2 & 0xffff0000u);
        ax += __uint_as_float(v3 << 16); ay += __uint_as_float(v3 & 0xffff0000u);
    }
    for (; e < end; ++e) {
        const uint v = xrow[(size_t)srcidx[e] * 64 + lane];
        ax += __uint_as_float(v << 16); ay += __uint_as_float(v & 0xffff0000u);
    }
    const uint packed = ((uint)f2bf(ay) << 16) | (uint)f2bf(ax);
    ((uint*)aggb)[(size_t)node * 64 + lane] = packed;
}

// ---------------------------------------------------------------------------
// out[50000,256] = aggb @ W12 + b2   via bf16 MFMA 16x16x32.
// Block: 256 rows x 256 cols, 8 waves (2Mx4N -> wave = 64 rows x 128 cols).
// Full K=128 of Bt staged in 64KB LDS, XOR-swizzled 16B chunks (T2).
// ---------------------------------------------------------------------------
__global__ __launch_bounds__(512) void mfma_gemm(const ushort* __restrict__ aggb,
                                                 const ushort* __restrict__ w12t,
                                                 const float* __restrict__ b2,
                                                 float* __restrict__ out) {
    __shared__ ushort bt[256 * 128];               // 64 KB
    const int tid = threadIdx.x;

    // stage Bt[n][k] (row = 256B = 16 chunks of 16B); chunk s -> slot s^(n&7)
#pragma unroll
    for (int it = 0; it < 8; ++it) {
        const int i = tid + it * 512;              // 0..4095
        const int n = i >> 4, s = i & 15;
        const uint4 v = *(const uint4*)(w12t + (size_t)i * 8);
        *(uint4*)(&bt[(n << 7) + ((s ^ (n & 7)) << 3)]) = v;
    }
    __syncthreads();

    const int lane = tid & 63;
    const int w    = tid >> 6;
    const int rbase = blockIdx.x * 256 + (w >> 1) * 64;
    const int cbase = (w & 1) * 128;
    const int l15 = lane & 15;
    const int oct = lane >> 4;

    f32x4 acc[4][8];
#pragma unroll
    for (int m = 0; m < 4; ++m)
#pragma unroll
        for (int n = 0; n < 8; ++n)
            acc[m][n] = (f32x4){0.f, 0.f, 0.f, 0.f};

#pragma unroll
    for (int kk = 0; kk < 4; ++kk) {               // k = kk*32 + oct*8 + j
        bf16x8 afr[4];
#pragma unroll
        for (int m = 0; m < 4; ++m) {
            int row = rbase + m * 16 + l15;
            row = row < N_NODES ? row : N_NODES - 1;   // tail clamp (discarded)
            afr[m] = *(const bf16x8*)(aggb + (size_t)row * IN_CH + kk * 32 + oct * 8);
        }
#pragma unroll
        for (int n = 0; n < 8; ++n) {
            const int col  = cbase + n * 16 + l15;
            const int slot = (kk * 4 + oct) ^ (col & 7);
            const bf16x8 bfr = *(const bf16x8*)(&bt[(col << 7) + (slot << 3)]);
#pragma unroll
            for (int m = 0; m < 4; ++m)
                acc[m][n] = __builtin_amdgcn_mfma_f32_16x16x32_bf16(
                    afr[m], bfr, acc[m][n], 0, 0, 0);
        }
    }

    // epilogue: D col = lane&15, row = oct*4 + r  (verified m89/m91 layout)
#pragma unroll
    for (int m = 0; m < 4; ++m) {
        const int row0 = rbase + m * 16 + oct * 4;
#pragma unroll
        for (int n = 0; n < 8; ++n) {
            const int col = cbase + n * 16 + l15;
            const float bias = b2[col];
#pragma unroll
            for (int r = 0; r < 4; ++r) {
                const int row = row0 + r;
                if (row < N_NODES)
                    out[(size_t)row * OUT_CH + col] = acc[m][n][r] + bias;
            }
        }
    }
}

// ---------------------------------------------------------------------------
extern "C" void kernel_launch(void* const* d_in, const int* in_sizes, int n_in,
                              void* d_out, int out_size, void* d_ws, size_t ws_size,
                              hipStream_t stream) {
    const float* x  = (const float*)d_in[0];
    const int*   ei = (const int*)d_in[1];      // [2, N_EDGES] int32
    const float* W1 = (const float*)d_in[2];
    const float* b1 = (const float*)d_in[3];
    const float* W2 = (const float*)d_in[4];
    float* out = (float*)d_out;

    // workspace layout (bytes)
    char* ws = (char*)d_ws;
    ushort* xb      = (ushort*)(ws + 0);                 // 12,800,000
    ushort* aggb    = (ushort*)(ws + 12800000);          // 12,800,000
    ushort* W12t    = (ushort*)(ws + 25600000);          //     65,536
    float*  b2      = (float*) (ws + 25665536);          //      1,024
    int*    rowptr  = (int*)   (ws + 25666560);          //    200,004
    int*    cursor  = (int*)   (ws + 25866564);          //    200,000
    int*    srcidx  = (int*)   (ws + 26066564);          //  3,200,000
    int*    tilesum = (int*)   (ws + 29266564);          //        392  -> ~29.27 MB

    // 1) collapse MLP -> bf16 W12^T + f32 b2
    build_w12<<<dim3(IN_CH + 1), dim3(256), 0, stream>>>(W1, b1, W2, W12t, b2);

    // 2) x -> bf16
    cvt_bf16<<<dim3((N_NODES * IN_CH / 4 + 255) / 256), dim3(256), 0, stream>>>(x, xb);

    // 3) CSR build: memset, histogram, hierarchical scan, fill
    hipMemsetAsync(rowptr, 0, (N_NODES + 1) * sizeof(int), stream);
    hist_dst<<<dim3((N_EDGES + 255) / 256), dim3(256), 0, stream>>>(ei, rowptr);
    scan_tiles<<<dim3(N_TILES), dim3(SCAN_TILE), 0, stream>>>(rowptr, tilesum);
    scan_sums<<<dim3(1), dim3(128), 0, stream>>>(tilesum);
    add_offsets<<<dim3(N_TILES), dim3(SCAN_TILE), 0, stream>>>(rowptr, tilesum, cursor);
    fill_csr<<<dim3((N_EDGES + 255) / 256), dim3(256), 0, stream>>>(ei, cursor, srcidx);

    // 4) gather (residual folded): aggb[n] = x[n] + sum x[src]   (bf16)
    gather_bf16<<<dim3(N_NODES * 64 / 256), dim3(256), 0, stream>>>(
        xb, rowptr, srcidx, aggb);

    // 5) out = aggb @ W12 + b2   (bf16 MFMA)
    mfma_gemm<<<dim3((N_NODES + 255) / 256), dim3(512), 0, stream>>>(
        aggb, W12t, b2, out);
}

// Round 5
// 157.904 us; speedup vs baseline: 11.3144x; 1.1179x over previous
//
#include <hip/hip_runtime.h>

#define N_NODES 50000
#define N_EDGES 800000
#define IN_CH   128
#define HID_CH  512
#define OUT_CH  256

#define SCAN_TILE 512
#define N_TILES   ((N_NODES + SCAN_TILE - 1) / SCAN_TILE)   // 98 (= buckets)
#define P1_EPT    8
#define P1_EPB    (512 * P1_EPT)                            // 4096 edges/block
#define P1_BLOCKS ((N_EDGES + P1_EPB - 1) / P1_EPB)         // 196

typedef __attribute__((ext_vector_type(8))) short bf16x8;
typedef __attribute__((ext_vector_type(4))) float f32x4;

static __device__ __forceinline__ ushort f2bf(float f) {
    uint u = __float_as_uint(f);
    uint r = u + 0x7fffu + ((u >> 16) & 1u);   // RNE; inputs are finite
    return (ushort)(r >> 16);
}

// ---------------------------------------------------------------------------
// W12t[j][i] = sum_k W1[i][k]*W2[k][j]  (bf16, TRANSPOSED: [256][128])
// b2[j]     = sum_k b1[k]*W2[k][j]     (f32)
// ---------------------------------------------------------------------------
__global__ void build_w12(const float* __restrict__ W1,
                          const float* __restrict__ b1,
                          const float* __restrict__ W2,
                          ushort* __restrict__ W12t,
                          float* __restrict__ b2) {
    const int i = blockIdx.x;        // 0..128 (128 == bias row)
    const int j = threadIdx.x;       // 0..255
    const float* arow = (i < IN_CH) ? (W1 + (size_t)i * HID_CH) : b1;
    float acc = 0.f;
#pragma unroll 8
    for (int k = 0; k < HID_CH; ++k)
        acc = fmaf(arow[k], W2[(size_t)k * OUT_CH + j], acc);
    if (i < IN_CH) W12t[(size_t)j * IN_CH + i] = f2bf(acc);
    else           b2[j] = acc;
}

// ---------------------------------------------------------------------------
// x (f32) -> xb (bf16)
// ---------------------------------------------------------------------------
__global__ void cvt_bf16(const float* __restrict__ x, ushort* __restrict__ xb) {
    const int i = blockIdx.x * 256 + threadIdx.x;      // group of 4 elements
    if (i >= N_NODES * IN_CH / 4) return;
    const float4 v = *(const float4*)(x + (size_t)i * 4);
    ushort4 o;
    o.x = f2bf(v.x); o.y = f2bf(v.y); o.z = f2bf(v.z); o.w = f2bf(v.w);
    *(ushort4*)(xb + (size_t)i * 4) = o;
}

// ---------------------------------------------------------------------------
// CSR build: histogram + hierarchical scan
// ---------------------------------------------------------------------------
__global__ void hist_dst(const int* __restrict__ ei, int* __restrict__ rowptr) {
    const int e = blockIdx.x * 256 + threadIdx.x;
    if (e < N_EDGES) atomicAdd(&rowptr[ei[N_EDGES + e] + 1], 1);
}

__global__ __launch_bounds__(SCAN_TILE) void scan_tiles(int* __restrict__ rowptr,
                                                        int* __restrict__ tilesum) {
    __shared__ int s[SCAN_TILE];
    const int t = threadIdx.x;
    const int g = blockIdx.x * SCAN_TILE + t;
    const int v = (g < N_NODES) ? rowptr[g + 1] : 0;
    s[t] = v;
    __syncthreads();
#pragma unroll
    for (int off = 1; off < SCAN_TILE; off <<= 1) {
        const int u = (t >= off) ? s[t - off] : 0;
        __syncthreads();
        s[t] += u;
        __syncthreads();
    }
    if (g < N_NODES) rowptr[g + 1] = s[t];
    if (t == SCAN_TILE - 1) tilesum[blockIdx.x] = s[t];
}

__global__ __launch_bounds__(128) void scan_sums(int* __restrict__ tilesum) {
    __shared__ int s[128];
    const int t = threadIdx.x;
    const int v = (t < N_TILES) ? tilesum[t] : 0;
    s[t] = v;
    __syncthreads();
#pragma unroll
    for (int off = 1; off < 128; off <<= 1) {
        const int u = (t >= off) ? s[t - off] : 0;
        __syncthreads();
        s[t] += u;
        __syncthreads();
    }
    if (t < N_TILES) tilesum[t] = s[t] - v;            // exclusive = rowptr[b*512]
}

// add tile offsets; seed per-bucket pair cursors (bucketcur[b] = rowptr[b*512])
__global__ __launch_bounds__(SCAN_TILE) void add_offsets(int* __restrict__ rowptr,
                                                         const int* __restrict__ tilesum,
                                                         int* __restrict__ bucketcur) {
    if (threadIdx.x == 0) bucketcur[blockIdx.x] = tilesum[blockIdx.x];
    const int g = blockIdx.x * SCAN_TILE + threadIdx.x;
    if (g >= N_NODES) return;
    rowptr[g + 1] += tilesum[blockIdx.x];
}

// ---------------------------------------------------------------------------
// Pass 1: partition edges into 98 dst-buckets (512 nodes each), packed uint32
// (bkt<<25 | src<<9 | dst&511). Bucket-contiguous coalesced writes.
// ---------------------------------------------------------------------------
__global__ __launch_bounds__(512) void partition_edges(const int* __restrict__ ei,
                                                       int* __restrict__ bucketcur,
                                                       uint* __restrict__ pairbuf) {
    __shared__ uint stage[P1_EPB];                 // 16 KB
    __shared__ int cnt[128], off[128], cur[128], base[128];
    const int t = threadIdx.x;
    const int e0 = blockIdx.x * P1_EPB;

    if (t < 128) cnt[t] = 0;
    __syncthreads();

    uint pk[P1_EPT];
    int  bk[P1_EPT];
    bool vl[P1_EPT];
#pragma unroll
    for (int i = 0; i < P1_EPT; ++i) {
        const int e = e0 + i * 512 + t;
        vl[i] = (e < N_EDGES);
        if (vl[i]) {
            const int src = ei[e];
            const int dst = ei[N_EDGES + e];
            const int b = dst >> 9;
            bk[i] = b;
            pk[i] = ((uint)b << 25) | ((uint)src << 9) | (uint)(dst & 511);
            atomicAdd(&cnt[b], 1);
        }
    }
    __syncthreads();

    // exclusive scan of cnt[0..127] -> off
    if (t < 128) off[t] = cnt[t];
    __syncthreads();
#pragma unroll
    for (int d = 1; d < 128; d <<= 1) {
        int u = 0;
        if (t < 128 && t >= d) u = off[t - d];
        __syncthreads();
        if (t < 128 && t >= d) off[t] += u;
        __syncthreads();
    }
    if (t < 128) {
        off[t] -= cnt[t];                          // exclusive
        cur[t] = off[t];
        if (t < N_TILES && cnt[t] > 0)
            base[t] = atomicAdd(&bucketcur[t], cnt[t]);
    }
    __syncthreads();

#pragma unroll
    for (int i = 0; i < P1_EPT; ++i)
        if (vl[i]) {
            const int lp = atomicAdd(&cur[bk[i]], 1);
            stage[lp] = pk[i];
        }
    __syncthreads();

    const int TOT = off[127] + cnt[127];
    for (int idx = t; idx < TOT; idx += 512) {
        const uint p = stage[idx];
        const int b = (int)(p >> 25);
        pairbuf[base[b] + (idx - off[b])] = p;
    }
}

// ---------------------------------------------------------------------------
// Pass 2: per-bucket CSR fill. LDS cursors; srcidx writes stay in a ~32 KB
// window -> single-XCD L2, lines written back once.
// ---------------------------------------------------------------------------
__global__ __launch_bounds__(512) void bucket_fill(const uint* __restrict__ pairbuf,
                                                   const int* __restrict__ rowptr,
                                                   int* __restrict__ srcidx) {
    __shared__ int cur[SCAN_TILE];
    const int b = blockIdx.x;
    const int t = threadIdx.x;
    const int nbase = b * SCAN_TILE;
    const int gi = nbase + t;
    cur[t] = rowptr[gi <= N_NODES ? gi : N_NODES];
    __syncthreads();
    const int S = rowptr[nbase];
    const int top = (nbase + SCAN_TILE <= N_NODES) ? nbase + SCAN_TILE : N_NODES;
    const int E = rowptr[top];
    for (int i = S + t; i < E; i += 512) {
        const uint p = pairbuf[i];
        const int ld  = (int)(p & 511u);
        const int src = (int)((p >> 9) & 0xFFFFu);
        const int pos = atomicAdd(&cur[ld], 1);
        srcidx[pos] = src;
    }
}

// ---------------------------------------------------------------------------
// Gather (bf16 rows, f32 accumulate): aggb[n] = x[n] + sum_{e in in(n)} x[src]
// One wave per node; lane l holds channels [2l,2l+1] packed in one uint.
// ---------------------------------------------------------------------------
__global__ __launch_bounds__(256) void gather_bf16(const ushort* __restrict__ xb,
                                                   const int* __restrict__ rowptr,
                                                   const int* __restrict__ srcidx,
                                                   ushort* __restrict__ aggb) {
    const int node = (int)((blockIdx.x * 256u + threadIdx.x) >> 6);
    const int lane = threadIdx.x & 63;
    if (node >= N_NODES) return;
    const uint* xrow = (const uint*)xb;            // 64 uints per node row
    const uint self = xrow[(size_t)node * 64 + lane];
    float ax = __uint_as_float(self << 16);
    float ay = __uint_as_float(self & 0xffff0000u);
    int e = rowptr[node];
    const int end = rowptr[node + 1];
    for (; e + 8 <= end; e += 8) {
        uint v[8];
#pragma unroll
        for (int i = 0; i < 8; ++i) {
            const int s = srcidx[e + i];
            v[i] = xrow[(size_t)s * 64 + lane];
        }
#pragma unroll
        for (int i = 0; i < 8; ++i) {
            ax += __uint_as_float(v[i] << 16);
            ay += __uint_as_float(v[i] & 0xffff0000u);
        }
    }
    for (; e < end; ++e) {
        const uint v = xrow[(size_t)srcidx[e] * 64 + lane];
        ax += __uint_as_float(v << 16); ay += __uint_as_float(v & 0xffff0000u);
    }
    const uint packed = ((uint)f2bf(ay) << 16) | (uint)f2bf(ax);
    ((uint*)aggb)[(size_t)node * 64 + lane] = packed;
}

// ---------------------------------------------------------------------------
// out[50000,256] = aggb @ W12 + b2   via bf16 MFMA 16x16x32.
// ---------------------------------------------------------------------------
__global__ __launch_bounds__(512) void mfma_gemm(const ushort* __restrict__ aggb,
                                                 const ushort* __restrict__ w12t,
                                                 const float* __restrict__ b2,
                                                 float* __restrict__ out) {
    __shared__ ushort bt[256 * 128];               // 64 KB
    const int tid = threadIdx.x;

#pragma unroll
    for (int it = 0; it < 8; ++it) {
        const int i = tid + it * 512;              // 0..4095
        const int n = i >> 4, s = i & 15;
        const uint4 v = *(const uint4*)(w12t + (size_t)i * 8);
        *(uint4*)(&bt[(n << 7) + ((s ^ (n & 7)) << 3)]) = v;
    }
    __syncthreads();

    const int lane = tid & 63;
    const int w    = tid >> 6;
    const int rbase = blockIdx.x * 256 + (w >> 1) * 64;
    const int cbase = (w & 1) * 128;
    const int l15 = lane & 15;
    const int oct = lane >> 4;

    f32x4 acc[4][8];
#pragma unroll
    for (int m = 0; m < 4; ++m)
#pragma unroll
        for (int n = 0; n < 8; ++n)
            acc[m][n] = (f32x4){0.f, 0.f, 0.f, 0.f};

#pragma unroll
    for (int kk = 0; kk < 4; ++kk) {               // k = kk*32 + oct*8 + j
        bf16x8 afr[4];
#pragma unroll
        for (int m = 0; m < 4; ++m) {
            int row = rbase + m * 16 + l15;
            row = row < N_NODES ? row : N_NODES - 1;
            afr[m] = *(const bf16x8*)(aggb + (size_t)row * IN_CH + kk * 32 + oct * 8);
        }
#pragma unroll
        for (int n = 0; n < 8; ++n) {
            const int col  = cbase + n * 16 + l15;
            const int slot = (kk * 4 + oct) ^ (col & 7);
            const bf16x8 bfr = *(const bf16x8*)(&bt[(col << 7) + (slot << 3)]);
#pragma unroll
            for (int m = 0; m < 4; ++m)
                acc[m][n] = __builtin_amdgcn_mfma_f32_16x16x32_bf16(
                    afr[m], bfr, acc[m][n], 0, 0, 0);
        }
    }

#pragma unroll
    for (int m = 0; m < 4; ++m) {
        const int row0 = rbase + m * 16 + oct * 4;
#pragma unroll
        for (int n = 0; n < 8; ++n) {
            const int col = cbase + n * 16 + l15;
            const float bias = b2[col];
#pragma unroll
            for (int r = 0; r < 4; ++r) {
                const int row = row0 + r;
                if (row < N_NODES)
                    out[(size_t)row * OUT_CH + col] = acc[m][n][r] + bias;
            }
        }
    }
}

// ---------------------------------------------------------------------------
extern "C" void kernel_launch(void* const* d_in, const int* in_sizes, int n_in,
                              void* d_out, int out_size, void* d_ws, size_t ws_size,
                              hipStream_t stream) {
    const float* x  = (const float*)d_in[0];
    const int*   ei = (const int*)d_in[1];      // [2, N_EDGES] int32
    const float* W1 = (const float*)d_in[2];
    const float* b1 = (const float*)d_in[3];
    const float* W2 = (const float*)d_in[4];
    float* out = (float*)d_out;

    // workspace layout (bytes)
    char* ws = (char*)d_ws;
    ushort* xb        = (ushort*)(ws + 0);               // 12,800,000
    ushort* aggb      = (ushort*)(ws + 12800000);        // 12,800,000
    uint*   pairbuf   = (uint*)  (ws + 12800000);        // 3,200,000 (aliases aggb;
                                                         //  disjoint lifetime)
    ushort* W12t      = (ushort*)(ws + 25600000);        //     65,536
    float*  b2        = (float*) (ws + 25665536);        //      1,024
    int*    rowptr    = (int*)   (ws + 25666560);        //    200,004
    int*    bucketcur = (int*)   (ws + 25866564);        //        392
    int*    srcidx    = (int*)   (ws + 26066564);        //  3,200,000
    int*    tilesum   = (int*)   (ws + 29266564);        //        392

    // 1) collapse MLP -> bf16 W12^T + f32 b2
    build_w12<<<dim3(IN_CH + 1), dim3(256), 0, stream>>>(W1, b1, W2, W12t, b2);

    // 2) x -> bf16
    cvt_bf16<<<dim3((N_NODES * IN_CH / 4 + 255) / 256), dim3(256), 0, stream>>>(x, xb);

    // 3) CSR build: hist, hierarchical scan (+ bucket cursor seed)
    hipMemsetAsync(rowptr, 0, (N_NODES + 1) * sizeof(int), stream);
    hist_dst<<<dim3((N_EDGES + 255) / 256), dim3(256), 0, stream>>>(ei, rowptr);
    scan_tiles<<<dim3(N_TILES), dim3(SCAN_TILE), 0, stream>>>(rowptr, tilesum);
    scan_sums<<<dim3(1), dim3(128), 0, stream>>>(tilesum);
    add_offsets<<<dim3(N_TILES), dim3(SCAN_TILE), 0, stream>>>(rowptr, tilesum, bucketcur);

    // 4) two-pass bucketed fill (replaces scattered fill_csr)
    partition_edges<<<dim3(P1_BLOCKS), dim3(512), 0, stream>>>(ei, bucketcur, pairbuf);
    bucket_fill<<<dim3(N_TILES), dim3(512), 0, stream>>>(pairbuf, rowptr, srcidx);

    // 5) gather (residual folded): aggb[n] = x[n] + sum x[src]   (bf16)
    gather_bf16<<<dim3(N_NODES * 64 / 256), dim3(256), 0, stream>>>(
        xb, rowptr, srcidx, aggb);

    // 6) out = aggb @ W12 + b2   (bf16 MFMA)
    mfma_gemm<<<dim3((N_NODES + 255) / 256), dim3(512), 0, stream>>>(
        aggb, W12t, b2, out);
}

// Round 6
// 153.341 us; speedup vs baseline: 11.6510x; 1.0298x over previous
//
#include <hip/hip_runtime.h>

#define N_NODES 50000
#define N_EDGES 800000
#define IN_CH   128
#define HID_CH  512
#define OUT_CH  256

#define SCAN_TILE 512
#define N_TILES   ((N_NODES + SCAN_TILE - 1) / SCAN_TILE)   // 98 (= buckets)
#define P1_EPT    8
#define P1_EPB    (512 * P1_EPT)                            // 4096 edges/block
#define P1_BLOCKS ((N_EDGES + P1_EPB - 1) / P1_EPB)         // 196

typedef __attribute__((ext_vector_type(8))) short bf16x8;
typedef __attribute__((ext_vector_type(4))) float f32x4;

static __device__ __forceinline__ ushort f2bf(float f) {
    uint u = __float_as_uint(f);
    uint r = u + 0x7fffu + ((u >> 16) & 1u);   // RNE; inputs are finite
    return (ushort)(r >> 16);
}

// ---------------------------------------------------------------------------
// W12t[j][i] = sum_k W1[i][k]*W2[k][j]  (bf16, TRANSPOSED: [256][128])
// b2[j]     = sum_k b1[k]*W2[k][j]     (f32)
// ---------------------------------------------------------------------------
__global__ void build_w12(const float* __restrict__ W1,
                          const float* __restrict__ b1,
                          const float* __restrict__ W2,
                          ushort* __restrict__ W12t,
                          float* __restrict__ b2) {
    const int i = blockIdx.x;        // 0..128 (128 == bias row)
    const int j = threadIdx.x;       // 0..255
    const float* arow = (i < IN_CH) ? (W1 + (size_t)i * HID_CH) : b1;
    float acc = 0.f;
#pragma unroll 8
    for (int k = 0; k < HID_CH; ++k)
        acc = fmaf(arow[k], W2[(size_t)k * OUT_CH + j], acc);
    if (i < IN_CH) W12t[(size_t)j * IN_CH + i] = f2bf(acc);
    else           b2[j] = acc;
}

// ---------------------------------------------------------------------------
// x (f32) -> xb (bf16); first 49 blocks also zero rowptr[0..50000]
// (replaces a hipMemsetAsync whose rocclr fill kernel cost 42 us/replay)
// ---------------------------------------------------------------------------
__global__ void cvt_bf16(const float* __restrict__ x, ushort* __restrict__ xb,
                         int* __restrict__ rowptr) {
    const int bid = blockIdx.x;
    if (bid < 49) {
        const int base = bid * 1024 + (int)threadIdx.x * 4;   // int index
#pragma unroll
        for (int r = 0; r < 4; ++r)
            if (base + r <= N_NODES) rowptr[base + r] = 0;
    }
    const int i = bid * 256 + threadIdx.x;             // group of 4 elements
    if (i >= N_NODES * IN_CH / 4) return;
    const float4 v = *(const float4*)(x + (size_t)i * 4);
    ushort4 o;
    o.x = f2bf(v.x); o.y = f2bf(v.y); o.z = f2bf(v.z); o.w = f2bf(v.w);
    *(ushort4*)(xb + (size_t)i * 4) = o;
}

// ---------------------------------------------------------------------------
// CSR build: histogram + hierarchical scan
// ---------------------------------------------------------------------------
__global__ void hist_dst(const int* __restrict__ ei, int* __restrict__ rowptr) {
    const int e = blockIdx.x * 256 + threadIdx.x;
    if (e < N_EDGES) atomicAdd(&rowptr[ei[N_EDGES + e] + 1], 1);
}

__global__ __launch_bounds__(SCAN_TILE) void scan_tiles(int* __restrict__ rowptr,
                                                        int* __restrict__ tilesum) {
    __shared__ int s[SCAN_TILE];
    const int t = threadIdx.x;
    const int g = blockIdx.x * SCAN_TILE + t;
    const int v = (g < N_NODES) ? rowptr[g + 1] : 0;
    s[t] = v;
    __syncthreads();
#pragma unroll
    for (int off = 1; off < SCAN_TILE; off <<= 1) {
        const int u = (t >= off) ? s[t - off] : 0;
        __syncthreads();
        s[t] += u;
        __syncthreads();
    }
    if (g < N_NODES) rowptr[g + 1] = s[t];
    if (t == SCAN_TILE - 1) tilesum[blockIdx.x] = s[t];
}

__global__ __launch_bounds__(128) void scan_sums(int* __restrict__ tilesum) {
    __shared__ int s[128];
    const int t = threadIdx.x;
    const int v = (t < N_TILES) ? tilesum[t] : 0;
    s[t] = v;
    __syncthreads();
#pragma unroll
    for (int off = 1; off < 128; off <<= 1) {
        const int u = (t >= off) ? s[t - off] : 0;
        __syncthreads();
        s[t] += u;
        __syncthreads();
    }
    if (t < N_TILES) tilesum[t] = s[t] - v;            // exclusive = rowptr[b*512]
}

// add tile offsets; seed per-bucket pair cursors (bucketcur[b] = rowptr[b*512])
__global__ __launch_bounds__(SCAN_TILE) void add_offsets(int* __restrict__ rowptr,
                                                         const int* __restrict__ tilesum,
                                                         int* __restrict__ bucketcur) {
    if (threadIdx.x == 0) bucketcur[blockIdx.x] = tilesum[blockIdx.x];
    const int g = blockIdx.x * SCAN_TILE + threadIdx.x;
    if (g >= N_NODES) return;
    rowptr[g + 1] += tilesum[blockIdx.x];
}

// ---------------------------------------------------------------------------
// Pass 1: partition edges into 98 dst-buckets (512 nodes each), packed uint32
// (bkt<<25 | src<<9 | dst&511). Bucket-contiguous coalesced writes.
// ---------------------------------------------------------------------------
__global__ __launch_bounds__(512) void partition_edges(const int* __restrict__ ei,
                                                       int* __restrict__ bucketcur,
                                                       uint* __restrict__ pairbuf) {
    __shared__ uint stage[P1_EPB];                 // 16 KB
    __shared__ int cnt[128], off[128], cur[128], base[128];
    const int t = threadIdx.x;
    const int e0 = blockIdx.x * P1_EPB;

    if (t < 128) cnt[t] = 0;
    __syncthreads();

    uint pk[P1_EPT];
    int  bk[P1_EPT];
    bool vl[P1_EPT];
#pragma unroll
    for (int i = 0; i < P1_EPT; ++i) {
        const int e = e0 + i * 512 + t;
        vl[i] = (e < N_EDGES);
        if (vl[i]) {
            const int src = ei[e];
            const int dst = ei[N_EDGES + e];
            const int b = dst >> 9;
            bk[i] = b;
            pk[i] = ((uint)b << 25) | ((uint)src << 9) | (uint)(dst & 511);
            atomicAdd(&cnt[b], 1);
        }
    }
    __syncthreads();

    // exclusive scan of cnt[0..127] -> off
    if (t < 128) off[t] = cnt[t];
    __syncthreads();
#pragma unroll
    for (int d = 1; d < 128; d <<= 1) {
        int u = 0;
        if (t < 128 && t >= d) u = off[t - d];
        __syncthreads();
        if (t < 128 && t >= d) off[t] += u;
        __syncthreads();
    }
    if (t < 128) {
        off[t] -= cnt[t];                          // exclusive
        cur[t] = off[t];
        if (t < N_TILES && cnt[t] > 0)
            base[t] = atomicAdd(&bucketcur[t], cnt[t]);
    }
    __syncthreads();

#pragma unroll
    for (int i = 0; i < P1_EPT; ++i)
        if (vl[i]) {
            const int lp = atomicAdd(&cur[bk[i]], 1);
            stage[lp] = pk[i];
        }
    __syncthreads();

    const int TOT = off[127] + cnt[127];
    for (int idx = t; idx < TOT; idx += 512) {
        const uint p = stage[idx];
        const int b = (int)(p >> 25);
        pairbuf[base[b] + (idx - off[b])] = p;
    }
}

// ---------------------------------------------------------------------------
// Pass 2: per-bucket CSR fill. LDS cursors; srcidx writes stay in a ~32 KB
// window -> single-XCD L2, lines written back once.
// ---------------------------------------------------------------------------
__global__ __launch_bounds__(512) void bucket_fill(const uint* __restrict__ pairbuf,
                                                   const int* __restrict__ rowptr,
                                                   int* __restrict__ srcidx) {
    __shared__ int cur[SCAN_TILE];
    const int b = blockIdx.x;
    const int t = threadIdx.x;
    const int nbase = b * SCAN_TILE;
    const int gi = nbase + t;
    cur[t] = rowptr[gi <= N_NODES ? gi : N_NODES];
    __syncthreads();
    const int S = rowptr[nbase];
    const int top = (nbase + SCAN_TILE <= N_NODES) ? nbase + SCAN_TILE : N_NODES;
    const int E = rowptr[top];
    for (int i = S + t; i < E; i += 512) {
        const uint p = pairbuf[i];
        const int ld  = (int)(p & 511u);
        const int src = (int)((p >> 9) & 0xFFFFu);
        const int pos = atomicAdd(&cur[ld], 1);
        srcidx[pos] = src;
    }
}

// ---------------------------------------------------------------------------
// Gather (bf16 rows, f32 accumulate): aggb[n] = x[n] + sum_{e in in(n)} x[src]
// One wave per node; lane l holds channels [2l,2l+1] packed in one uint.
// ---------------------------------------------------------------------------
__global__ __launch_bounds__(256) void gather_bf16(const ushort* __restrict__ xb,
                                                   const int* __restrict__ rowptr,
                                                   const int* __restrict__ srcidx,
                                                   ushort* __restrict__ aggb) {
    const int node = (int)((blockIdx.x * 256u + threadIdx.x) >> 6);
    const int lane = threadIdx.x & 63;
    if (node >= N_NODES) return;
    const uint* xrow = (const uint*)xb;            // 64 uints per node row
    const uint self = xrow[(size_t)node * 64 + lane];
    float ax = __uint_as_float(self << 16);
    float ay = __uint_as_float(self & 0xffff0000u);
    int e = rowptr[node];
    const int end = rowptr[node + 1];
    for (; e + 8 <= end; e += 8) {
        uint v[8];
#pragma unroll
        for (int i = 0; i < 8; ++i) {
            const int s = srcidx[e + i];
            v[i] = xrow[(size_t)s * 64 + lane];
        }
#pragma unroll
        for (int i = 0; i < 8; ++i) {
            ax += __uint_as_float(v[i] << 16);
            ay += __uint_as_float(v[i] & 0xffff0000u);
        }
    }
    for (; e < end; ++e) {
        const uint v = xrow[(size_t)srcidx[e] * 64 + lane];
        ax += __uint_as_float(v << 16); ay += __uint_as_float(v & 0xffff0000u);
    }
    const uint packed = ((uint)f2bf(ay) << 16) | (uint)f2bf(ax);
    ((uint*)aggb)[(size_t)node * 64 + lane] = packed;
}

// ---------------------------------------------------------------------------
// out[50000,256] = aggb @ W12 + b2   via bf16 MFMA 16x16x32.
// ---------------------------------------------------------------------------
__global__ __launch_bounds__(512) void mfma_gemm(const ushort* __restrict__ aggb,
                                                 const ushort* __restrict__ w12t,
                                                 const float* __restrict__ b2,
                                                 float* __restrict__ out) {
    __shared__ ushort bt[256 * 128];               // 64 KB
    const int tid = threadIdx.x;

#pragma unroll
    for (int it = 0; it < 8; ++it) {
        const int i = tid + it * 512;              // 0..4095
        const int n = i >> 4, s = i & 15;
        const uint4 v = *(const uint4*)(w12t + (size_t)i * 8);
        *(uint4*)(&bt[(n << 7) + ((s ^ (n & 7)) << 3)]) = v;
    }
    __syncthreads();

    const int lane = tid & 63;
    const int w    = tid >> 6;
    const int rbase = blockIdx.x * 256 + (w >> 1) * 64;
    const int cbase = (w & 1) * 128;
    const int l15 = lane & 15;
    const int oct = lane >> 4;

    f32x4 acc[4][8];
#pragma unroll
    for (int m = 0; m < 4; ++m)
#pragma unroll
        for (int n = 0; n < 8; ++n)
            acc[m][n] = (f32x4){0.f, 0.f, 0.f, 0.f};

#pragma unroll
    for (int kk = 0; kk < 4; ++kk) {               // k = kk*32 + oct*8 + j
        bf16x8 afr[4];
#pragma unroll
        for (int m = 0; m < 4; ++m) {
            int row = rbase + m * 16 + l15;
            row = row < N_NODES ? row : N_NODES - 1;
            afr[m] = *(const bf16x8*)(aggb + (size_t)row * IN_CH + kk * 32 + oct * 8);
        }
#pragma unroll
        for (int n = 0; n < 8; ++n) {
            const int col  = cbase + n * 16 + l15;
            const int slot = (kk * 4 + oct) ^ (col & 7);
            const bf16x8 bfr = *(const bf16x8*)(&bt[(col << 7) + (slot << 3)]);
#pragma unroll
            for (int m = 0; m < 4; ++m)
                acc[m][n] = __builtin_amdgcn_mfma_f32_16x16x32_bf16(
                    afr[m], bfr, acc[m][n], 0, 0, 0);
        }
    }

#pragma unroll
    for (int m = 0; m < 4; ++m) {
        const int row0 = rbase + m * 16 + oct * 4;
#pragma unroll
        for (int n = 0; n < 8; ++n) {
            const int col = cbase + n * 16 + l15;
            const float bias = b2[col];
#pragma unroll
            for (int r = 0; r < 4; ++r) {
                const int row = row0 + r;
                if (row < N_NODES)
                    out[(size_t)row * OUT_CH + col] = acc[m][n][r] + bias;
            }
        }
    }
}

// ---------------------------------------------------------------------------
extern "C" void kernel_launch(void* const* d_in, const int* in_sizes, int n_in,
                              void* d_out, int out_size, void* d_ws, size_t ws_size,
                              hipStream_t stream) {
    const float* x  = (const float*)d_in[0];
    const int*   ei = (const int*)d_in[1];      // [2, N_EDGES] int32
    const float* W1 = (const float*)d_in[2];
    const float* b1 = (const float*)d_in[3];
    const float* W2 = (const float*)d_in[4];
    float* out = (float*)d_out;

    // workspace layout (bytes)
    char* ws = (char*)d_ws;
    ushort* xb        = (ushort*)(ws + 0);               // 12,800,000
    ushort* aggb      = (ushort*)(ws + 12800000);        // 12,800,000
    uint*   pairbuf   = (uint*)  (ws + 12800000);        // 3,200,000 (aliases aggb;
                                                         //  disjoint lifetime)
    ushort* W12t      = (ushort*)(ws + 25600000);        //     65,536
    float*  b2        = (float*) (ws + 25665536);        //      1,024
    int*    rowptr    = (int*)   (ws + 25666560);        //    200,004
    int*    bucketcur = (int*)   (ws + 25866564);        //        392
    int*    srcidx    = (int*)   (ws + 26066564);        //  3,200,000
    int*    tilesum   = (int*)   (ws + 29266564);        //        392

    // 1) collapse MLP -> bf16 W12^T + f32 b2
    build_w12<<<dim3(IN_CH + 1), dim3(256), 0, stream>>>(W1, b1, W2, W12t, b2);

    // 2) x -> bf16 (also zeroes rowptr, replacing hipMemsetAsync)
    cvt_bf16<<<dim3((N_NODES * IN_CH / 4 + 255) / 256), dim3(256), 0, stream>>>(
        x, xb, rowptr);

    // 3) CSR build: hist, hierarchical scan (+ bucket cursor seed)
    hist_dst<<<dim3((N_EDGES + 255) / 256), dim3(256), 0, stream>>>(ei, rowptr);
    scan_tiles<<<dim3(N_TILES), dim3(SCAN_TILE), 0, stream>>>(rowptr, tilesum);
    scan_sums<<<dim3(1), dim3(128), 0, stream>>>(tilesum);
    add_offsets<<<dim3(N_TILES), dim3(SCAN_TILE), 0, stream>>>(rowptr, tilesum, bucketcur);

    // 4) two-pass bucketed fill
    partition_edges<<<dim3(P1_BLOCKS), dim3(512), 0, stream>>>(ei, bucketcur, pairbuf);
    bucket_fill<<<dim3(N_TILES), dim3(512), 0, stream>>>(pairbuf, rowptr, srcidx);

    // 5) gather (residual folded): aggb[n] = x[n] + sum x[src]   (bf16)
    gather_bf16<<<dim3(N_NODES * 64 / 256), dim3(256), 0, stream>>>(
        xb, rowptr, srcidx, aggb);

    // 6) out = aggb @ W12 + b2   (bf16 MFMA)
    mfma_gemm<<<dim3((N_NODES + 255) / 256), dim3(512), 0, stream>>>(
        aggb, W12t, b2, out);
}